// Round 4
// baseline (172.736 us; speedup 1.0000x reference)
//
#include <hip/hip_runtime.h>
#include <hip/hip_bf16.h>

typedef _Float16 half8 __attribute__((ext_vector_type(8)));
typedef _Float16 half4_t __attribute__((ext_vector_type(4)));
typedef _Float16 half2_t __attribute__((ext_vector_type(2)));
typedef float floatx4 __attribute__((ext_vector_type(4)));

#define MFMA16(a, b, c) __builtin_amdgcn_mfma_f32_16x16x32_f16(a, b, c, 0, 0, 0)
#define MASKVAL (-30000.0f)
// 1/sqrt(128) * log2(e), folded into wq during prep
#define QSCALE 0.1275261529f

// ---------------------------------------------------------------------------
// Kernel 1 (prep): x fp32->fp16 (blocks 0..4095), weight transpose+convert
// (blocks 4096..4607). QSCALE folded into wqt.
// ---------------------------------------------------------------------------
__global__ __launch_bounds__(256) void prep(
    const float* __restrict__ x, const float* __restrict__ wq,
    const float* __restrict__ wk, const float* __restrict__ wv,
    const float* __restrict__ wo, _Float16* __restrict__ xh,
    _Float16* __restrict__ wqt, _Float16* __restrict__ wkt,
    _Float16* __restrict__ wvt, _Float16* __restrict__ wot) {
  int bx = blockIdx.x, tid = threadIdx.x;
  if (bx < 4096) {
    size_t idx = (size_t)bx * 2048 + tid * 8;
    float4 f0 = *(const float4*)&x[idx];
    float4 f1 = *(const float4*)&x[idx + 4];
    half8 h;
    h[0] = (_Float16)f0.x; h[1] = (_Float16)f0.y; h[2] = (_Float16)f0.z; h[3] = (_Float16)f0.w;
    h[4] = (_Float16)f1.x; h[5] = (_Float16)f1.y; h[6] = (_Float16)f1.z; h[7] = (_Float16)f1.w;
    *(half8*)&xh[idx] = h;
    return;
  }
  __shared__ float T[32][36];
  const float* src;
  _Float16* dst;
  int R, C, r0, c0;
  float sc = 1.0f;
  if (bx < 4480) {
    int b2 = bx - 4096;
    int p = b2 >> 7, t = b2 & 127;
    src = (p == 0) ? wq : (p == 1) ? wk : wv;
    dst = (p == 0) ? wqt : (p == 1) ? wkt : wvt;
    if (p == 0) sc = QSCALE;
    R = 1024; C = 128;
    r0 = (t & 31) * 32; c0 = (t >> 5) * 32;
  } else {
    int t = bx - 4480;
    src = wo; dst = wot;
    R = 128; C = 1024;
    r0 = (t & 3) * 32; c0 = (t >> 2) * 32;
  }
  {
    int row = tid >> 3, c4 = (tid & 7) * 4;
    float4 f = *(const float4*)&src[(size_t)(r0 + row) * C + c0 + c4];
    T[row][c4] = f.x; T[row][c4 + 1] = f.y; T[row][c4 + 2] = f.z; T[row][c4 + 3] = f.w;
  }
  __syncthreads();
  {
    int cc = tid >> 3, r4 = (tid & 7) * 4;
    half4_t h;
    h[0] = (_Float16)(T[r4 + 0][cc] * sc);
    h[1] = (_Float16)(T[r4 + 1][cc] * sc);
    h[2] = (_Float16)(T[r4 + 2][cc] * sc);
    h[3] = (_Float16)(T[r4 + 3][cc] * sc);
    *(half4_t*)&dst[(size_t)(c0 + cc) * R + r0 + r4] = h;
  }
}

// ---------------------------------------------------------------------------
// Kernel 2: QKV projection from xh (fp16). Grid (128 m-tiles, 3 proj), BK=128
// -> 8 iterations. V written transposed Vt[(b*128+h)*2048+s].
// ---------------------------------------------------------------------------
__global__ __launch_bounds__(256) void qkv_gemm(
    const _Float16* __restrict__ xh, const _Float16* __restrict__ wqt,
    const _Float16* __restrict__ wkt, const _Float16* __restrict__ wvt,
    _Float16* __restrict__ Qh, _Float16* __restrict__ Kh,
    _Float16* __restrict__ Vt) {
  __shared__ _Float16 A_lds[64 * 136];
  __shared__ _Float16 B_lds[128 * 136];
  int tid = threadIdx.x;
  int w = tid >> 6, lane = tid & 63, quad = lane >> 4, l16 = lane & 15;
  int m0 = blockIdx.x * 64;
  int proj = blockIdx.y;
  const _Float16* wt = (proj == 0) ? wqt : (proj == 1) ? wkt : wvt;
  floatx4 zero = {0.f, 0.f, 0.f, 0.f};
  floatx4 acc[8];
#pragma unroll
  for (int t = 0; t < 8; t++) acc[t] = zero;

  int arow = tid >> 2, akk = (tid & 3) * 32;
  int brow = tid >> 1, bkk = (tid & 1) * 64;

  for (int k0 = 0; k0 < 1024; k0 += 128) {
#pragma unroll
    for (int i = 0; i < 4; i++)
      *(half8*)&A_lds[arow * 136 + akk + i * 8] =
          *(const half8*)&xh[(size_t)(m0 + arow) * 1024 + k0 + akk + i * 8];
#pragma unroll
    for (int i = 0; i < 8; i++)
      *(half8*)&B_lds[brow * 136 + bkk + i * 8] =
          *(const half8*)&wt[(size_t)brow * 1024 + k0 + bkk + i * 8];
    __syncthreads();
    half8 a[4];
#pragma unroll
    for (int c = 0; c < 4; c++)
      a[c] = *(const half8*)&A_lds[(w * 16 + l16) * 136 + c * 32 + quad * 8];
#pragma unroll
    for (int t = 0; t < 8; t++)
#pragma unroll
      for (int c = 0; c < 4; c++) {
        half8 b = *(const half8*)&B_lds[(t * 16 + l16) * 136 + c * 32 + quad * 8];
        acc[t] = MFMA16(a[c], b, acc[t]);
      }
    __syncthreads();
  }
#pragma unroll
  for (int t = 0; t < 8; t++)
#pragma unroll
    for (int r = 0; r < 4; r++) {
      int row = m0 + w * 16 + quad * 4 + r;
      int col = t * 16 + l16;
      _Float16 v = (_Float16)acc[t][r];
      if (proj == 0)
        Qh[(size_t)row * 128 + col] = v;
      else if (proj == 1)
        Kh[(size_t)row * 128 + col] = v;
      else {
        int bb = row >> 11, s = row & 2047;
        Vt[((size_t)(bb * 128 + col)) * 2048 + s] = v;
      }
    }
}

// ---------------------------------------------------------------------------
// Kernel 3: flash-attention partial, ONE 128-key chunk per block (no K-loop).
// Grid (16 kc, 32 qt reversed, 4 b); ~1088 live blocks, 4 waves each; wave
// owns 16 queries. Two barriers total. P reuses K's LDS region after barrier.
// ---------------------------------------------------------------------------
__global__ __launch_bounds__(256) void attn_partial(
    const _Float16* __restrict__ Qh, const _Float16* __restrict__ Kh,
    const _Float16* __restrict__ Vt, _Float16* __restrict__ Opart,
    float* __restrict__ Ml) {
  __shared__ _Float16 K_lds[128 * 136];  // keys x feat; later reused for P
  __shared__ _Float16 V_lds[128 * 136];  // feat x keys
  int tid = threadIdx.x;
  int w = tid >> 6, lane = tid & 63, quad = lane >> 4, l16 = lane & 15;
  int kc = blockIdx.x;
  int qt = 31 - (int)blockIdx.y;
  int b = blockIdx.z;
  int nkc = (qt + 2) >> 1;  // ceil((qt*64+64)/128)
  if (kc >= nkc) return;
  int q0 = qt * 64;
  int k0 = kc * 128;
  int qw0 = q0 + w * 16;
  int sidx = (b * 32 + qt) * 16 + kc;
  bool domask = (kc == nkc - 1);

  const _Float16* Kb = Kh + (size_t)b * 2048 * 128;
  const _Float16* Vb = Vt + (size_t)b * 128 * 2048;

  // stage K (128 keys x 128 feat) and V (128 feat x 128 keys)
  {
    int row = tid >> 1, koff = (tid & 1) * 64;
#pragma unroll
    for (int i = 0; i < 8; i++)
      *(half8*)&K_lds[row * 136 + koff + i * 8] =
          *(const half8*)&Kb[(size_t)(k0 + row) * 128 + koff + i * 8];
#pragma unroll
    for (int i = 0; i < 8; i++)
      *(half8*)&V_lds[row * 136 + koff + i * 8] =
          *(const half8*)&Vb[(size_t)row * 2048 + k0 + koff + i * 8];
  }

  half8 aq[4];
  {
    const _Float16* qbase = Qh + (size_t)(b * 2048 + qw0 + l16) * 128;
#pragma unroll
    for (int c = 0; c < 4; c++) aq[c] = *(const half8*)&qbase[c * 32 + quad * 8];
  }
  __syncthreads();

  // number of live 16-key subtiles for this wave (diagonal-aware)
  int ntl = ((qw0 + 15 - k0) >> 4) + 1;
  ntl = ntl > 8 ? 8 : ntl;

  floatx4 zero = {0.f, 0.f, 0.f, 0.f};
  floatx4 sa[8];
#pragma unroll
  for (int t = 0; t < 8; t++) sa[t] = zero;
#pragma unroll
  for (int t = 0; t < 8; t++)
    if (t < ntl) {
#pragma unroll
      for (int c = 0; c < 4; c++) {
        half8 bk = *(const half8*)&K_lds[(t * 16 + l16) * 136 + c * 32 + quad * 8];
        sa[t] = MFMA16(aq[c], bk, sa[t]);
      }
    }

  float m_r[4], l_r[4];
  float p[8][4];
#pragma unroll
  for (int r = 0; r < 4; r++) {
    int query = qw0 + quad * 4 + r;
    float mx = MASKVAL;
#pragma unroll
    for (int t = 0; t < 8; t++) {
      if (t < ntl) {
        float s = sa[t][r];
        if (domask && (k0 + t * 16 + l16 > query)) s = MASKVAL;
        p[t][r] = s;
        mx = fmaxf(mx, s);
      } else {
        p[t][r] = 0.f;  // dead subtile -> zero weight
      }
    }
#pragma unroll
    for (int off = 1; off < 16; off <<= 1) mx = fmaxf(mx, __shfl_xor(mx, off));
    float rs = 0.f;
#pragma unroll
    for (int t = 0; t < 8; t++)
      if (t < ntl) {
        float e = exp2f(p[t][r] - mx);
        p[t][r] = e;
        rs += e;
      }
#pragma unroll
    for (int off = 1; off < 16; off <<= 1) rs += __shfl_xor(rs, off);
    m_r[r] = mx;
    l_r[r] = rs;
  }

  __syncthreads();  // everyone done reading K; reuse K_lds for P
  _Float16* P = K_lds + w * 16 * 136;
#pragma unroll
  for (int r = 0; r < 4; r++)
#pragma unroll
    for (int t = 0; t < 8; t++)
      P[(quad * 4 + r) * 136 + t * 16 + l16] = (_Float16)p[t][r];

  floatx4 O[8];
#pragma unroll
  for (int t = 0; t < 8; t++) O[t] = zero;
  int nc2 = (ntl + 1) >> 1;
#pragma unroll
  for (int c2 = 0; c2 < 4; c2++)
    if (c2 < nc2) {
      half8 ap = *(const half8*)&P[l16 * 136 + c2 * 32 + quad * 8];
#pragma unroll
      for (int t = 0; t < 8; t++) {
        half8 bv = *(const half8*)&V_lds[(t * 16 + l16) * 136 + c2 * 32 + quad * 8];
        O[t] = MFMA16(ap, bv, O[t]);
      }
    }

  size_t obase = (size_t)sidx * 8192;
#pragma unroll
  for (int t = 0; t < 8; t++)
#pragma unroll
    for (int r = 0; r < 4; r++)
      Opart[obase + (size_t)(w * 16 + quad * 4 + r) * 128 + t * 16 + l16] = (_Float16)O[t][r];
  if (l16 == 0)
#pragma unroll
    for (int r = 0; r < 4; r++) {
      int row = w * 16 + quad * 4 + r;
      Ml[(size_t)sidx * 128 + row * 2] = m_r[r];
      Ml[(size_t)sidx * 128 + row * 2 + 1] = l_r[r];
    }
}

// ---------------------------------------------------------------------------
// Kernel 3b: combine partials (up to 16/row). One wave per query row,
// two-pass so no dynamically-indexed register arrays.
// ---------------------------------------------------------------------------
__global__ __launch_bounds__(256) void attn_combine(
    const _Float16* __restrict__ Opart, const float* __restrict__ Ml,
    _Float16* __restrict__ ctx) {
  int tid = threadIdx.x;
  int w = tid >> 6, lane = tid & 63;
  int row = blockIdx.x * 4 + w;
  int b = row >> 11, s = row & 2047;
  int qt = s >> 6, ri = s & 63;
  int nkc = (qt + 2) >> 1;
  int sidx0 = (b * 32 + qt) * 16;
  float M = MASKVAL;
  for (int i = 0; i < nkc; i++)
    M = fmaxf(M, Ml[(size_t)(sidx0 + i) * 128 + ri * 2]);
  float L = 0.f, a0 = 0.f, a1 = 0.f;
  for (int i = 0; i < nkc; i++) {
    float mi = Ml[(size_t)(sidx0 + i) * 128 + ri * 2];
    float li = Ml[(size_t)(sidx0 + i) * 128 + ri * 2 + 1];
    float sc = exp2f(mi - M);
    L += li * sc;
    half2_t o = *(const half2_t*)&Opart[(size_t)(sidx0 + i) * 8192 + (size_t)ri * 128 + lane * 2];
    a0 += sc * (float)o[0];
    a1 += sc * (float)o[1];
  }
  float inv = 1.f / L;
  half2_t hv;
  hv[0] = (_Float16)(a0 * inv);
  hv[1] = (_Float16)(a1 * inv);
  *(half2_t*)&ctx[(size_t)row * 128 + lane * 2] = hv;
}

// ---------------------------------------------------------------------------
// Kernel 4: out projection ctx[8192,128] x wo[128,1024] -> fp32 out.
// ---------------------------------------------------------------------------
__global__ __launch_bounds__(256) void out_gemm(
    const _Float16* __restrict__ ctx, const _Float16* __restrict__ wot,
    float* __restrict__ out) {
  __shared__ _Float16 A_lds[64 * 136];
  __shared__ _Float16 B_lds[128 * 136];
  int tid = threadIdx.x;
  int w = tid >> 6, lane = tid & 63, quad = lane >> 4, l16 = lane & 15;
  int m0 = blockIdx.x * 64, n0 = blockIdx.y * 128;
  {
    int row = tid >> 2, kk = (tid & 3) * 32;
#pragma unroll
    for (int i = 0; i < 4; i++)
      *(half8*)&A_lds[row * 136 + kk + i * 8] =
          *(const half8*)&ctx[(size_t)(m0 + row) * 128 + kk + i * 8];
  }
  {
    int n = tid >> 1, kk = (tid & 1) * 64;
#pragma unroll
    for (int i = 0; i < 8; i++)
      *(half8*)&B_lds[n * 136 + kk + i * 8] =
          *(const half8*)&wot[(size_t)(n0 + n) * 128 + kk + i * 8];
  }
  __syncthreads();
  floatx4 zero = {0.f, 0.f, 0.f, 0.f};
  floatx4 acc[8];
#pragma unroll
  for (int t = 0; t < 8; t++) acc[t] = zero;
  half8 a[4];
#pragma unroll
  for (int c = 0; c < 4; c++) a[c] = *(const half8*)&A_lds[(w * 16 + l16) * 136 + c * 32 + quad * 8];
#pragma unroll
  for (int t = 0; t < 8; t++)
#pragma unroll
    for (int c = 0; c < 4; c++) {
      half8 b = *(const half8*)&B_lds[(t * 16 + l16) * 136 + c * 32 + quad * 8];
      acc[t] = MFMA16(a[c], b, acc[t]);
    }
#pragma unroll
  for (int t = 0; t < 8; t++)
#pragma unroll
    for (int r = 0; r < 4; r++) {
      int row = m0 + w * 16 + quad * 4 + r;
      out[(size_t)row * 1024 + n0 + t * 16 + l16] = acc[t][r];
    }
}

// ---------------------------------------------------------------------------
extern "C" void kernel_launch(void* const* d_in, const int* in_sizes, int n_in,
                              void* d_out, int out_size, void* d_ws, size_t ws_size,
                              hipStream_t stream) {
  const float* x = (const float*)d_in[0];
  const float* wq = (const float*)d_in[1];
  const float* wk = (const float*)d_in[2];
  const float* wv = (const float*)d_in[3];
  const float* wo = (const float*)d_in[4];
  char* ws = (char*)d_ws;
  _Float16* wqt = (_Float16*)(ws + 0);
  _Float16* wkt = (_Float16*)(ws + 262144);
  _Float16* wvt = (_Float16*)(ws + 524288);
  _Float16* wot = (_Float16*)(ws + 786432);
  _Float16* xh  = (_Float16*)(ws + 1048576);              // 16 MB
  _Float16* Qh  = (_Float16*)(ws + 17825792);             // 2 MB
  _Float16* Kh  = (_Float16*)(ws + 19922944);             // 2 MB
  _Float16* Vt  = (_Float16*)(ws + 22020096);             // 2 MB
  _Float16* ctxh = (_Float16*)(ws + 24117248);            // 2 MB
  _Float16* Opart = (_Float16*)(ws + 26214400);           // 2048 * 16 KB = 32 MB
  float* Ml = (float*)(ws + 59768832);                    // 1 MB
  float* out = (float*)d_out;

  prep<<<4608, 256, 0, stream>>>(x, wq, wk, wv, wo, xh, wqt, wkt, wvt, wot);
  qkv_gemm<<<dim3(128, 3), 256, 0, stream>>>(xh, wqt, wkt, wvt, Qh, Kh, Vt);
  attn_partial<<<dim3(16, 32, 4), 256, 0, stream>>>(Qh, Kh, Vt, Opart, Ml);
  attn_combine<<<2048, 256, 0, stream>>>(Opart, Ml, ctxh);
  out_gemm<<<dim3(128, 8), 256, 0, stream>>>(ctxh, wot, out);
}